// Round 13
// baseline (293.724 us; speedup 1.0000x reference)
//
#include <hip/hip_runtime.h>
#include <stdint.h>

// ---------------------------------------------------------------- helpers
__device__ __forceinline__ float bf_lo(uint32_t w) { return __uint_as_float(w << 16); }
__device__ __forceinline__ float bf_hi(uint32_t w) { return __uint_as_float(w & 0xffff0000u); }
__device__ __forceinline__ float bfu(uint16_t u) { return __uint_as_float((uint32_t)u << 16); }
__device__ __forceinline__ uint16_t f2bf(float f) {
    uint32_t u = __float_as_uint(f);
    uint32_t r = ((u >> 16) & 1u) + 0x7fffu;   // round-to-nearest-even
    return (uint16_t)((u + r) >> 16);
}
__device__ __forceinline__ uint32_t pk2bf(float a, float b) {
    return (uint32_t)f2bf(a) | ((uint32_t)f2bf(b) << 16);
}
__device__ __forceinline__ void gload_lds16(const void* g, void* l) {
    __builtin_amdgcn_global_load_lds(
        (const __attribute__((address_space(1))) void*)g,
        (__attribute__((address_space(3))) void*)l, 16, 0, 0);
}

typedef __attribute__((ext_vector_type(8))) short bf16x8;
typedef __attribute__((ext_vector_type(4))) float f32x4;

#define LOG2E 1.4426950408889634f
#define QSC2  (0.25f * LOG2E)      // fold 1/sqrt(dk) and log2e into Q

// gemm epilogue modes
#define M_BF16 0   // bf16 out [M][128]
#define M_QS   1   // bf16 out, scaled by QSC2
#define M_SIG  2   // sigmoid(acc+bias), bf16 out
#define M_KVIK 3   // interleaved K slot of [M][256]
#define M_KVIV 4   // interleaved V slot
#define M_GV   5   // sigmoid(acc+bias) * aux(bf16 [M][128]) -> interleaved V slot
#define M_LN1  6   // LN(residf32 + acc) -> bf16 out
#define M_LN2  7   // LN(residbf16 + acc) -> f32 out
#define M_B8   8   // cols 0..7 only -> f32 [M][8] (bias projections)
#define M_BIND 10  // CSR finalize pseudo-job (binD): no GEMM, grid-parallel

// ---------------------------------------------------------------- bucket capacity
#define NBKT_MAX 512
#define CAPSHIFT 13
#define BCAP (1 << CAPSHIFT)

struct GemmJob {
    const uint16_t* A; const uint16_t* WT; const float* bias;
    const uint16_t* aux; const void* resid;
    const float* lng; const float* lnb;
    void* out; int M; int mode; int i0; int i1;
};
struct GemmJobs { GemmJob j[6]; };

// stage a 128x128 bf16 tile (XOR-swizzled global source, linear LDS dest)
__device__ __forceinline__ void stage_tile(const uint16_t* __restrict__ g,
                                           uint16_t* lds, int tid, int wid)
{
#pragma unroll
    for (int it = 0; it < 8; ++it) {
        int idx = it * 256 + tid;
        int r = idx >> 4, c = idx & 15;
        int gc = c ^ (r & 7);
        gload_lds16(g + (size_t)r * 128 + gc * 8,
                    lds + (size_t)(it * 256 + wid * 64) * 8);
    }
}

// ---------------------------------------------------------------- MFMA GEMM (multi-job via blockIdx.y, per-job A/M)
__global__ __launch_bounds__(256) void multi_gemm_k(GemmJobs jobs)
{
    __shared__ uint16_t As[128 * 128];
    __shared__ uint16_t Ws[128 * 128];
    const GemmJob jb = jobs.j[blockIdx.y];
    const int tid = threadIdx.x;
    const int wid = tid >> 6;
    const int lane = tid & 63;
    const int mode = jb.mode;

    if (mode == M_BIND) {
        // binD: per-bucket per-segment hist + LDS scan -> offs/ends, then scatter
        const uint2* tmp   = (const uint2*)jb.A;
        const int* bktcnt  = (const int*)jb.WT;
        int* offs          = (int*)jb.bias;
        int* ends          = (int*)jb.aux;
        int* sorted        = (int*)jb.resid;
        const int spb = jb.i0, NN = jb.i1;
        int* sh  = (int*)As;               // spb ints
        int* wtb = (int*)Ws;               // 4 ints
        int b = blockIdx.x, t = tid;
        int s0 = b * spb;
        if (s0 >= NN) return;
        int segs = min(spb, NN - s0);
        int p0 = b << CAPSHIFT;
        int p1 = p0 + bktcnt[b];
        for (int i = t; i < segs; i += 256) sh[i] = 0;
        __syncthreads();
        for (int i = p0 + t; i < p1; i += 256)
            atomicAdd(&sh[(int)tmp[i].x - s0], 1);
        __syncthreads();
        int e_per = (spb + 255) >> 8;
        int loc[4], cv[4]; int ls = 0;
#pragma unroll 4
        for (int j = 0; j < 4; ++j) {
            if (j < e_per) {
                int idx = t * e_per + j;
                int v = (idx < segs) ? sh[idx] : 0;
                loc[j] = ls; cv[j] = v; ls += v;
            }
        }
        int sc = ls;
#pragma unroll
        for (int o = 1; o < 64; o <<= 1) { int x = __shfl_up(sc, o); if (lane >= o) sc += x; }
        if (lane == 63) wtb[wid] = sc;
        __syncthreads();
        int add = 0;
        for (int i = 0; i < wid; i++) add += wtb[i];
        int texcl = add + sc - ls;
#pragma unroll 4
        for (int j = 0; j < 4; ++j) {
            if (j < e_per) {
                int idx = t * e_per + j;
                if (idx < segs) {
                    int pos = p0 + texcl + loc[j];
                    offs[s0 + idx] = pos;
                    ends[s0 + idx] = pos + cv[j];
                    sh[idx] = pos;        // becomes cursor
                }
            }
        }
        __syncthreads();
        for (int i = p0 + t; i < p1; i += 256) {
            uint2 pr = tmp[i];
            int p = atomicAdd(&sh[(int)pr.x - s0], 1);
            sorted[p] = (int)pr.y;
        }
        return;
    }

    const int m0 = blockIdx.x * 128;
    if (m0 >= jb.M) return;
    const int M = jb.M;

    stage_tile(jb.A + (size_t)m0 * 128, As, tid, wid);
    stage_tile(jb.WT, Ws, tid, wid);
    __syncthreads();

    const int wr = wid >> 1, wc = wid & 1;
    const int l15 = lane & 15, l4 = lane >> 4;

    if (mode == M_B8) {
        // only cols 0..15 of WT are nonzero -> 16 MFMAs
        f32x4 acc[4];
#pragma unroll
        for (int i = 0; i < 4; i++) acc[i] = (f32x4){0.f, 0.f, 0.f, 0.f};
#pragma unroll
        for (int kk = 0; kk < 4; ++kk) {
            bf16x8 af0;
            {
                int r = l15;
                int cc = (kk * 4 + l4) ^ (r & 7);
                af0 = *(const bf16x8*)(Ws + r * 128 + cc * 8);
            }
#pragma unroll
            for (int mi = 0; mi < 4; ++mi) {
                int r = wr * 64 + mi * 16 + l15;
                int cc = (kk * 4 + l4) ^ (r & 7);
                bf16x8 bf = *(const bf16x8*)(As + r * 128 + cc * 8);
                acc[mi] = __builtin_amdgcn_mfma_f32_16x16x32_bf16(af0, bf, acc[mi], 0, 0, 0);
            }
        }
        if (wc == 0 && l4 < 2) {
#pragma unroll
            for (int mi = 0; mi < 4; ++mi) {
                int gm = m0 + wr * 64 + mi * 16 + l15;
                if (gm < M) {
                    f32x4 v = acc[mi];
                    *(float4*)((float*)jb.out + (size_t)gm * 8 + l4 * 4) =
                        make_float4(v.x, v.y, v.z, v.w);
                }
            }
        }
        return;
    }

    f32x4 acc[4][4];
#pragma unroll
    for (int i = 0; i < 4; i++)
#pragma unroll
        for (int j = 0; j < 4; j++) acc[i][j] = (f32x4){0.f, 0.f, 0.f, 0.f};

#pragma unroll
    for (int kk = 0; kk < 4; ++kk) {
        bf16x8 af[4], bff[4];
#pragma unroll
        for (int ni = 0; ni < 4; ++ni) {
            int r = wc * 64 + ni * 16 + l15;
            int cc = (kk * 4 + l4) ^ (r & 7);
            af[ni] = *(const bf16x8*)(Ws + r * 128 + cc * 8);
        }
#pragma unroll
        for (int mi = 0; mi < 4; ++mi) {
            int r = wr * 64 + mi * 16 + l15;
            int cc = (kk * 4 + l4) ^ (r & 7);
            bff[mi] = *(const bf16x8*)(As + r * 128 + cc * 8);
        }
#pragma unroll
        for (int ni = 0; ni < 4; ++ni)
#pragma unroll
            for (int mi = 0; mi < 4; ++mi)
                acc[ni][mi] = __builtin_amdgcn_mfma_f32_16x16x32_bf16(
                    af[ni], bff[mi], acc[ni][mi], 0, 0, 0);
    }

    if (mode == M_LN1 || mode == M_LN2) {
        __syncthreads();                      // all waves done reading Ws
        float* redS = (float*)Ws;             // [128][2]
        float* redQ = redS + 256;             // [128][2]
        float ps[4], qs[4];
#pragma unroll
        for (int mi = 0; mi < 4; ++mi) {
            int row = wr * 64 + mi * 16 + l15;
            int gm = m0 + row;
            float sum = 0.f, sq = 0.f;
#pragma unroll
            for (int ni = 0; ni < 4; ++ni) {
                int gn = wc * 64 + ni * 16 + l4 * 4;
                float r0 = 0.f, r1 = 0.f, r2 = 0.f, r3 = 0.f;
                if (gm < M) {
                    if (mode == M_LN1) {
                        float4 rv = *(const float4*)((const float*)jb.resid + (size_t)gm * 128 + gn);
                        r0 = rv.x; r1 = rv.y; r2 = rv.z; r3 = rv.w;
                    } else {
                        ushort4 rv = *(const ushort4*)((const uint16_t*)jb.resid + (size_t)gm * 128 + gn);
                        r0 = bfu(rv.x); r1 = bfu(rv.y); r2 = bfu(rv.z); r3 = bfu(rv.w);
                    }
                }
                f32x4 t = acc[ni][mi];
                t.x += r0; t.y += r1; t.z += r2; t.w += r3;
                acc[ni][mi] = t;
                sum += t.x + t.y + t.z + t.w;
                sq  += t.x * t.x + t.y * t.y + t.z * t.z + t.w * t.w;
            }
            sum += __shfl_xor(sum, 16); sum += __shfl_xor(sum, 32);
            sq  += __shfl_xor(sq, 16);  sq  += __shfl_xor(sq, 32);
            ps[mi] = sum; qs[mi] = sq;
        }
        if (l4 == 0) {
#pragma unroll
            for (int mi = 0; mi < 4; ++mi) {
                int row = wr * 64 + mi * 16 + l15;
                redS[row * 2 + wc] = ps[mi];
                redQ[row * 2 + wc] = qs[mi];
            }
        }
        __syncthreads();
#pragma unroll
        for (int mi = 0; mi < 4; ++mi) {
            int row = wr * 64 + mi * 16 + l15;
            int gm = m0 + row;
            if (gm >= M) continue;
            float S = redS[row * 2] + redS[row * 2 + 1];
            float Q = redQ[row * 2] + redQ[row * 2 + 1];
            float mean = S * (1.f / 128.f);
            float var  = Q * (1.f / 128.f) - mean * mean;
            float rstd = rsqrtf(var + 1e-5f);
#pragma unroll
            for (int ni = 0; ni < 4; ++ni) {
                int gn = wc * 64 + ni * 16 + l4 * 4;
                float4 gg = *(const float4*)(jb.lng + gn);
                float4 bb = *(const float4*)(jb.lnb + gn);
                f32x4 t = acc[ni][mi];
                float o0 = gg.x * (t.x - mean) * rstd + bb.x;
                float o1 = gg.y * (t.y - mean) * rstd + bb.y;
                float o2 = gg.z * (t.z - mean) * rstd + bb.z;
                float o3 = gg.w * (t.w - mean) * rstd + bb.w;
                if (mode == M_LN1) {
                    ushort4 o;
                    o.x = f2bf(o0); o.y = f2bf(o1); o.z = f2bf(o2); o.w = f2bf(o3);
                    *(ushort4*)((uint16_t*)jb.out + (size_t)gm * 128 + gn) = o;
                } else {
                    *(float4*)((float*)jb.out + (size_t)gm * 128 + gn) =
                        make_float4(o0, o1, o2, o3);
                }
            }
        }
        return;
    }

#pragma unroll
    for (int mi = 0; mi < 4; ++mi) {
        int gm = m0 + wr * 64 + mi * 16 + l15;
        if (gm >= M) continue;
#pragma unroll
        for (int ni = 0; ni < 4; ++ni) {
            int gn = wc * 64 + ni * 16 + l4 * 4;
            f32x4 v = acc[ni][mi];
            if (mode == M_SIG || mode == M_GV) {
                float4 bb = *(const float4*)(jb.bias + gn);
                v.x = 1.f / (1.f + __expf(-(v.x + bb.x)));
                v.y = 1.f / (1.f + __expf(-(v.y + bb.y)));
                v.z = 1.f / (1.f + __expf(-(v.z + bb.z)));
                v.w = 1.f / (1.f + __expf(-(v.w + bb.w)));
            }
            if (mode == M_QS) { v.x *= QSC2; v.y *= QSC2; v.z *= QSC2; v.w *= QSC2; }
            if (mode == M_GV) {
                ushort4 vs = *(const ushort4*)(jb.aux + (size_t)gm * 128 + gn);
                v.x *= bfu(vs.x); v.y *= bfu(vs.y); v.z *= bfu(vs.z); v.w *= bfu(vs.w);
            }
            if (mode == M_KVIK || mode == M_KVIV || mode == M_GV) {
                int which = (mode == M_KVIK) ? 0 : 2;
                uint16_t* op = (uint16_t*)jb.out + (size_t)gm * 256 + gn * 2 + which;
                *reinterpret_cast<uint32_t*>(op)     = pk2bf(v.x, v.y);
                *reinterpret_cast<uint32_t*>(op + 4) = pk2bf(v.z, v.w);
            } else {
                ushort4 o;
                o.x = f2bf(v.x); o.y = f2bf(v.y); o.z = f2bf(v.z); o.w = f2bf(v.w);
                *reinterpret_cast<ushort4*>((uint16_t*)jb.out + (size_t)gm * 128 + gn) = o;
            }
        }
    }
}

// ---------------------------------------------------------------- merged prep: binA FIRST, then weight transposes, then casts
#define PREP_BINA_BLKS 512
#define PREP_WT_BLKS   896    // 14 jobs x 64 blocks
#define PREP_CAST_BLKS 1536

struct WT14 { const float* src[14]; uint16_t* dst[14]; int nc[14]; int coff[14]; };

__global__ __launch_bounds__(256) void prep_k(
    const float* __restrict__ X, uint16_t* __restrict__ Xb, int n1,
    const float* __restrict__ Xs, uint16_t* __restrict__ Xsb, int n2,
    WT14 wt,
    const int* __restrict__ s1, const int* __restrict__ p1,
    const int* __restrict__ s2, const int* __restrict__ p2,
    int* __restrict__ bktcnt, uint2* __restrict__ tmp,
    int E1, int E2, int N, int shift, int nbkt, int chunk)
{
    __shared__ int hist[NBKT_MAX];
    __shared__ int lcur[NBKT_MAX];
    int bx = blockIdx.x;
    int t = threadIdx.x;
    if (bx < PREP_BINA_BLKS) {
        // binA: bucket-partition (seg,pay) pairs into fixed-capacity buckets
        int bid = bx;
        int Et = E1 + E2;
        int base = bid * chunk;
        int end = min(base + chunk, Et);
        for (int i = t; i < nbkt; i += 256) hist[i] = 0;
        __syncthreads();
        for (int i = base + t; i < end; i += 256) {
            int seg = (i < E1) ? s1[i] : N + s2[i - E1];
            atomicAdd(&hist[seg >> shift], 1);
        }
        __syncthreads();
        for (int i = t; i < nbkt; i += 256) {
            int c = hist[i];
            lcur[i] = (i << CAPSHIFT) + (c ? atomicAdd(&bktcnt[i], c) : 0);
        }
        __syncthreads();
        for (int i = base + t; i < end; i += 256) {
            int seg, pay;
            if (i < E1) { seg = s1[i]; pay = p1[i]; }
            else        { seg = N + s2[i - E1]; pay = p2[i - E1]; }
            int p = atomicAdd(&lcur[seg >> shift], 1);
            tmp[p] = make_uint2((uint32_t)seg, (uint32_t)pay);
        }
    } else if (bx < PREP_BINA_BLKS + PREP_WT_BLKS) {
        int pb = bx - PREP_BINA_BLKS;
        int y = pb >> 6, xx = pb & 63;
        const float* W = wt.src[y];
        uint16_t* WT = wt.dst[y];
        int nc = wt.nc[y], coff = wt.coff[y];
        int i = xx * 256 + t;
        int k = i >> 7, n = i & 127;
        float v;
        if (nc == 8) v = (n < 8) ? W[k * 8 + n] * LOG2E : 0.f;
        else         v = W[(size_t)k * nc + coff + n];
        WT[(size_t)n * 128 + k] = f2bf(v);
    } else {
        int i = (bx - PREP_BINA_BLKS - PREP_WT_BLKS) * 256 + t;
        int stride = PREP_CAST_BLKS * 256;
        for (; i < n1 + n2; i += stride) {
            float4 v;
            ushort4 o;
            if (i < n1) v = reinterpret_cast<const float4*>(X)[i];
            else        v = reinterpret_cast<const float4*>(Xs)[i - n1];
            o.x = f2bf(v.x); o.y = f2bf(v.y); o.z = f2bf(v.z); o.w = f2bf(v.w);
            if (i < n1) reinterpret_cast<ushort4*>(Xb)[i] = o;
            else        reinterpret_cast<ushort4*>(Xsb)[i - n1] = o;
        }
    }
}

// ---------------------------------------------------------------- self-attention (scalar index path, 8-edge batches)
#define SSTEP(KV, ACC)                                                           \
    {                                                                            \
        float s = q0 * bf_lo(KV.x) + q1 * bf_hi(KV.x);                           \
        s += __shfl_xor(s, 1); s += __shfl_xor(s, 2); s += __shfl_xor(s, 4);     \
        float w = exp2f(s + bs);                                                 \
        pa##ACC = fmaf(w, bf_lo(KV.y), pa##ACC);                                 \
        pb##ACC = fmaf(w, bf_hi(KV.y), pb##ACC);                                 \
        dn##ACC += w;                                                            \
    }

__global__ __launch_bounds__(128) void self_attn_k(
    const uint16_t* __restrict__ Qb, const uint16_t* __restrict__ kvi,
    const float* __restrict__ bias1,
    const int* __restrict__ offs, const int* __restrict__ ends,
    const int* __restrict__ sdst,
    const uint16_t* __restrict__ g16, uint16_t* __restrict__ Aout, int N)
{
    int lane = threadIdx.x & 63;
    int n = blockIdx.x * 2 + (threadIdx.x >> 6);
    if (n >= N) return;
    const int lane4 = lane * 4;
    uint32_t qw = *reinterpret_cast<const uint32_t*>(Qb + (size_t)n * 128 + 2 * lane);
    float q0 = bf_lo(qw), q1 = bf_hi(qw);
    float bs = bias1[(size_t)n * 8 + (lane >> 3)];
    int e0 = offs[n], e1 = ends[n];
    float dn0 = 0.f, pa0 = 0.f, pb0 = 0.f;
    float dn1 = 0.f, pa1 = 0.f, pb1 = 0.f;
    float dn2 = 0.f, pa2 = 0.f, pb2 = 0.f;
    float dn3 = 0.f, pa3 = 0.f, pb3 = 0.f;
    float dn4 = 0.f, pa4 = 0.f, pb4 = 0.f;
    float dn5 = 0.f, pa5 = 0.f, pb5 = 0.f;
    float dn6 = 0.f, pa6 = 0.f, pb6 = 0.f;
    float dn7 = 0.f, pa7 = 0.f, pb7 = 0.f;
    int e = e0;
    for (; e + 8 <= e1; e += 8) {
        const int* sp = sdst + __builtin_amdgcn_readfirstlane(e);
        int d0 = __builtin_amdgcn_readfirstlane(sp[0]);
        int d1 = __builtin_amdgcn_readfirstlane(sp[1]);
        int d2 = __builtin_amdgcn_readfirstlane(sp[2]);
        int d3 = __builtin_amdgcn_readfirstlane(sp[3]);
        int d4 = __builtin_amdgcn_readfirstlane(sp[4]);
        int d5 = __builtin_amdgcn_readfirstlane(sp[5]);
        int d6 = __builtin_amdgcn_readfirstlane(sp[6]);
        int d7 = __builtin_amdgcn_readfirstlane(sp[7]);
        uint2 kv0 = *reinterpret_cast<const uint2*>(kvi + ((size_t)d0 << 8) + lane4);
        uint2 kv1 = *reinterpret_cast<const uint2*>(kvi + ((size_t)d1 << 8) + lane4);
        uint2 kv2 = *reinterpret_cast<const uint2*>(kvi + ((size_t)d2 << 8) + lane4);
        uint2 kv3 = *reinterpret_cast<const uint2*>(kvi + ((size_t)d3 << 8) + lane4);
        uint2 kv4 = *reinterpret_cast<const uint2*>(kvi + ((size_t)d4 << 8) + lane4);
        uint2 kv5 = *reinterpret_cast<const uint2*>(kvi + ((size_t)d5 << 8) + lane4);
        uint2 kv6 = *reinterpret_cast<const uint2*>(kvi + ((size_t)d6 << 8) + lane4);
        uint2 kv7 = *reinterpret_cast<const uint2*>(kvi + ((size_t)d7 << 8) + lane4);
        SSTEP(kv0, 0) SSTEP(kv1, 1) SSTEP(kv2, 2) SSTEP(kv3, 3)
        SSTEP(kv4, 4) SSTEP(kv5, 5) SSTEP(kv6, 6) SSTEP(kv7, 7)
    }
    for (; e + 4 <= e1; e += 4) {
        const int* sp = sdst + __builtin_amdgcn_readfirstlane(e);
        int d0 = __builtin_amdgcn_readfirstlane(sp[0]);
        int d1 = __builtin_amdgcn_readfirstlane(sp[1]);
        int d2 = __builtin_amdgcn_readfirstlane(sp[2]);
        int d3 = __builtin_amdgcn_readfirstlane(sp[3]);
        uint2 kv0 = *reinterpret_cast<const uint2*>(kvi + ((size_t)d0 << 8) + lane4);
        uint2 kv1 = *reinterpret_cast<const uint2*>(kvi + ((size_t)d1 << 8) + lane4);
        uint2 kv2 = *reinterpret_cast<const uint2*>(kvi + ((size_t)d2 << 8) + lane4);
        uint2 kv3 = *reinterpret_cast<const uint2*>(kvi + ((size_t)d3 << 8) + lane4);
        SSTEP(kv0, 0) SSTEP(kv1, 1) SSTEP(kv2, 2) SSTEP(kv3, 3)
    }
    for (; e < e1; ++e) {
        int d0 = __builtin_amdgcn_readfirstlane(sdst[__builtin_amdgcn_readfirstlane(e)]);
        uint2 kv0 = *reinterpret_cast<const uint2*>(kvi + ((size_t)d0 << 8) + lane4);
        SSTEP(kv0, 0)
    }
    float den = ((dn0 + dn1) + (dn2 + dn3)) + ((dn4 + dn5) + (dn6 + dn7));
    float a0 = ((pa0 + pa1) + (pa2 + pa3)) + ((pa4 + pa5) + (pa6 + pa7));
    float a1 = ((pb0 + pb1) + (pb2 + pb3)) + ((pb4 + pb5) + (pb6 + pb7));
    float inv = 1.f / (den + 1e-30f);
    uint32_t gw = *reinterpret_cast<const uint32_t*>(g16 + (size_t)n * 128 + 2 * lane);
    a0 *= inv * bf_lo(gw); a1 *= inv * bf_hi(gw);
    *reinterpret_cast<uint32_t*>(Aout + (size_t)n * 128 + 2 * lane) = pk2bf(a0, a1);
}

// ---------------------------------------------------------------- cross-attention (scalar index path, 8-edge batches, V pre-gated)
#define CSTEP(KV, BSS, ACC)                                                      \
    {                                                                            \
        float s = q0 * bf_lo(KV.x) + q1 * bf_hi(KV.x);                           \
        s += __shfl_xor(s, 1); s += __shfl_xor(s, 2); s += __shfl_xor(s, 4);     \
        float w = exp2f(s + bt + BSS);                                           \
        pa##ACC = fmaf(w, bf_lo(KV.y), pa##ACC);                                 \
        pb##ACC = fmaf(w, bf_hi(KV.y), pb##ACC);                                 \
        dn##ACC += w;                                                            \
    }

__global__ __launch_bounds__(128) void cross_attn_k(
    const uint16_t* __restrict__ Qcb, const float* __restrict__ bias_t,
    const uint16_t* __restrict__ kvgi, const float* __restrict__ bias_s,
    const int* __restrict__ offs, const int* __restrict__ ends,
    const int* __restrict__ ssrc,
    const uint16_t* __restrict__ g16, uint16_t* __restrict__ Aout, int N)
{
    int lane = threadIdx.x & 63;
    int n = blockIdx.x * 2 + (threadIdx.x >> 6);
    if (n >= N) return;
    const int lane4 = lane * 4;
    const int head = lane >> 3;
    uint32_t qw = *reinterpret_cast<const uint32_t*>(Qcb + (size_t)n * 128 + 2 * lane);
    float q0 = bf_lo(qw), q1 = bf_hi(qw);
    float bt = bias_t[(size_t)n * 8 + head];
    int e0 = offs[n], e1 = ends[n];
    float dn0 = 0.f, pa0 = 0.f, pb0 = 0.f;
    float dn1 = 0.f, pa1 = 0.f, pb1 = 0.f;
    float dn2 = 0.f, pa2 = 0.f, pb2 = 0.f;
    float dn3 = 0.f, pa3 = 0.f, pb3 = 0.f;
    float dn4 = 0.f, pa4 = 0.f, pb4 = 0.f;
    float dn5 = 0.f, pa5 = 0.f, pb5 = 0.f;
    float dn6 = 0.f, pa6 = 0.f, pb6 = 0.f;
    float dn7 = 0.f, pa7 = 0.f, pb7 = 0.f;
    int e = e0;
    for (; e + 8 <= e1; e += 8) {
        const int* sp = ssrc + __builtin_amdgcn_readfirstlane(e);
        int d0 = __builtin_amdgcn_readfirstlane(sp[0]);
        int d1 = __builtin_amdgcn_readfirstlane(sp[1]);
        int d2 = __builtin_amdgcn_readfirstlane(sp[2]);
        int d3 = __builtin_amdgcn_readfirstlane(sp[3]);
        int d4 = __builtin_amdgcn_readfirstlane(sp[4]);
        int d5 = __builtin_amdgcn_readfirstlane(sp[5]);
        int d6 = __builtin_amdgcn_readfirstlane(sp[6]);
        int d7 = __builtin_amdgcn_readfirstlane(sp[7]);
        uint2 kv0 = *reinterpret_cast<const uint2*>(kvgi + ((size_t)d0 << 8) + lane4);
        uint2 kv1 = *reinterpret_cast<const uint2*>(kvgi + ((size_t)d1 << 8) + lane4);
        uint2 kv2 = *reinterpret_cast<const uint2*>(kvgi + ((size_t)d2 << 8) + lane4);
        uint2 kv3 = *reinterpret_cast<const uint2*>(kvgi + ((size_t)d3 << 8) + lane4);
        uint2 kv4 = *reinterpret_cast<const uint2*>(kvgi + ((size_t)d4 << 8) + lane4);
        uint2 kv5 = *reinterpret_cast<const uint2*>(kvgi + ((size_t)d5 << 8) + lane4);
        uint2 kv6 = *reinterpret_cast<const uint2*>(kvgi + ((size_t)d6 << 8) + lane4);
        uint2 kv7 = *reinterpret_cast<const uint2*>(kvgi + ((size_t)d7 << 8) + lane4);
        float bs0 = (bias_s + (size_t)d0 * 8)[head];
        float bs1 = (bias_s + (size_t)d1 * 8)[head];
        float bs2 = (bias_s + (size_t)d2 * 8)[head];
        float bs3 = (bias_s + (size_t)d3 * 8)[head];
        float bs4 = (bias_s + (size_t)d4 * 8)[head];
        float bs5 = (bias_s + (size_t)d5 * 8)[head];
        float bs6 = (bias_s + (size_t)d6 * 8)[head];
        float bs7 = (bias_s + (size_t)d7 * 8)[head];
        CSTEP(kv0, bs0, 0) CSTEP(kv1, bs1, 1) CSTEP(kv2, bs2, 2) CSTEP(kv3, bs3, 3)
        CSTEP(kv4, bs4, 4) CSTEP(kv5, bs5, 5) CSTEP(kv6, bs6, 6) CSTEP(kv7, bs7, 7)
    }
    for (; e + 4 <= e1; e += 4) {
        const int* sp = ssrc + __builtin_amdgcn_readfirstlane(e);
        int d0 = __builtin_amdgcn_readfirstlane(sp[0]);
        int d1 = __builtin_amdgcn_readfirstlane(sp[1]);
        int d2 = __builtin_amdgcn_readfirstlane(sp[2]);
        int d3 = __builtin_amdgcn_readfirstlane(sp[3]);
        uint2 kv0 = *reinterpret_cast<const uint2*>(kvgi + ((size_t)d0 << 8) + lane4);
        uint2 kv1 = *reinterpret_cast<const uint2*>(kvgi + ((size_t)d1 << 8) + lane4);
        uint2 kv2 = *reinterpret_cast<const uint2*>(kvgi + ((size_t)d2 << 8) + lane4);
        uint2 kv3 = *reinterpret_cast<const uint2*>(kvgi + ((size_t)d3 << 8) + lane4);
        float bs0 = (bias_s + (size_t)d0 * 8)[head];
        float bs1 = (bias_s + (size_t)d1 * 8)[head];
        float bs2 = (bias_s + (size_t)d2 * 8)[head];
        float bs3 = (bias_s + (size_t)d3 * 8)[head];
        CSTEP(kv0, bs0, 0) CSTEP(kv1, bs1, 1) CSTEP(kv2, bs2, 2) CSTEP(kv3, bs3, 3)
    }
    for (; e < e1; ++e) {
        int d0 = __builtin_amdgcn_readfirstlane(ssrc[__builtin_amdgcn_readfirstlane(e)]);
        uint2 kv0 = *reinterpret_cast<const uint2*>(kvgi + ((size_t)d0 << 8) + lane4);
        float bs0 = (bias_s + (size_t)d0 * 8)[head];
        CSTEP(kv0, bs0, 0)
    }
    float den = ((dn0 + dn1) + (dn2 + dn3)) + ((dn4 + dn5) + (dn6 + dn7));
    float a0 = ((pa0 + pa1) + (pa2 + pa3)) + ((pa4 + pa5) + (pa6 + pa7));
    float a1 = ((pb0 + pb1) + (pb2 + pb3)) + ((pb4 + pb5) + (pb6 + pb7));
    float inv = 1.f / (den + 1e-30f);
    uint32_t gw = *reinterpret_cast<const uint32_t*>(g16 + (size_t)n * 128 + 2 * lane);
    a0 *= inv * bf_lo(gw); a1 *= inv * bf_hi(gw);
    *reinterpret_cast<uint32_t*>(Aout + (size_t)n * 128 + 2 * lane) = pk2bf(a0, a1);
}

// ---------------------------------------------------------------- host
static inline size_t smax_(size_t a, size_t b) { return a > b ? a : b; }

extern "C" void kernel_launch(void* const* d_in, const int* in_sizes, int n_in,
                              void* d_out, int out_size, void* d_ws, size_t ws_size,
                              hipStream_t stream)
{
    const float* X          = (const float*)d_in[0];
    const float* Xs         = (const float*)d_in[1];
    const float* W_qkv      = (const float*)d_in[2];
    const float* w_bias     = (const float*)d_in[3];
    const float* W_gate     = (const float*)d_in[4];
    const float* b_gate     = (const float*)d_in[5];
    const float* W_o        = (const float*)d_in[6];
    const float* W_q        = (const float*)d_in[7];
    const float* W_kv       = (const float*)d_in[8];
    const float* w_bias_tgt = (const float*)d_in[9];
    const float* w_bias_src = (const float*)d_in[10];
    const float* W_gate_tgt = (const float*)d_in[11];
    const float* b_gate_tgt = (const float*)d_in[12];
    const float* W_gate_src = (const float*)d_in[13];
    const float* b_gate_src = (const float*)d_in[14];
    const float* W_o2       = (const float*)d_in[15];
    const float* ln1_g      = (const float*)d_in[16];
    const float* ln1_b      = (const float*)d_in[17];
    const float* ln2_g      = (const float*)d_in[18];
    const float* ln2_b      = (const float*)d_in[19];
    const int* nbr_src      = (const int*)d_in[20];
    const int* nbr_dst      = (const int*)d_in[21];
    const int* inc_tgt      = (const int*)d_in[22];
    const int* inc_src      = (const int*)d_in[23];

    const int N  = in_sizes[0] / 128;
    const int NS = in_sizes[1] / 128;
    const int E1 = in_sizes[20];
    const int E2 = in_sizes[22];
    const int Et = E1 + E2;
    const int NN = 2 * N;
    const int Npad  = (N + 127) & ~127;
    const int NSpad = (NS + 127) & ~127;

    // bucket geometry: spb segments/bucket, nbkt <= NBKT_MAX
    int shift = 8;
    while (((NN + (1 << shift) - 1) >> shift) > NBKT_MAX) ++shift;
    const int spb  = 1 << shift;
    const int nbkt = (NN + spb - 1) >> shift;

    char* ws = (char*)d_ws;
    size_t off = 0;
    auto alloc = [&](size_t bytes) -> void* {
        void* p = ws + off;
        off = (off + bytes + 255) & ~(size_t)255;
        return p;
    };

    uint16_t* Xb   = (uint16_t*)alloc((size_t)Npad * 128 * 2);
    uint16_t* Xsb  = (uint16_t*)alloc((size_t)NSpad * 128 * 2);
    uint16_t* WTq  = (uint16_t*)alloc((size_t)384 * 128 * 2);
    uint16_t* WTkv = (uint16_t*)alloc((size_t)256 * 128 * 2);
    uint16_t* WTg  = (uint16_t*)alloc((size_t)128 * 128 * 2);
    uint16_t* WTo  = (uint16_t*)alloc((size_t)128 * 128 * 2);
    uint16_t* WTq2 = (uint16_t*)alloc((size_t)128 * 128 * 2);
    uint16_t* WTgt = (uint16_t*)alloc((size_t)128 * 128 * 2);
    uint16_t* WTgs = (uint16_t*)alloc((size_t)128 * 128 * 2);
    uint16_t* WTo2 = (uint16_t*)alloc((size_t)128 * 128 * 2);
    uint16_t* WTb1 = (uint16_t*)alloc((size_t)128 * 128 * 2);   // w_bias pad
    uint16_t* WTbt = (uint16_t*)alloc((size_t)128 * 128 * 2);   // w_bias_tgt pad
    uint16_t* WTbs = (uint16_t*)alloc((size_t)128 * 128 * 2);   // w_bias_src pad
    size_t s1a = (size_t)Npad * 384 * 2;
    size_t s1b = (size_t)NSpad * 384 * 2;
    uint16_t* S1 = (uint16_t*)alloc(smax_(s1a, s1b));
    uint16_t* Qb   = S1;
    uint16_t* kvi  = S1 + (size_t)Npad * 128;
    uint16_t* kvgi = S1;
    uint16_t* V16  = S1 + (size_t)NSpad * 256;
    uint2* tmp  = (uint2*)alloc(((size_t)NBKT_MAX << CAPSHIFT) * 8);  // own buffer: binD (in gemm dispatch) overlaps S1 writers
    uint16_t* g16  = (uint16_t*)alloc((size_t)N * 128 * 2);
    uint16_t* Qcb  = (uint16_t*)alloc((size_t)N * 128 * 2);
    uint16_t* Awo  = (uint16_t*)alloc((size_t)Npad * 128 * 2);
    uint16_t* hb   = (uint16_t*)alloc((size_t)Npad * 128 * 2);
    float*    b8a  = (float*)alloc((size_t)N * 8 * 4);
    float*    b8s  = (float*)alloc((size_t)NS * 8 * 4);
    int* offs   = (int*)alloc((size_t)NN * 4);
    int* ends   = (int*)alloc((size_t)NN * 4);
    int* sorted = (int*)alloc(((size_t)NBKT_MAX << CAPSHIFT) * 4);
    int* bktcnt = (int*)alloc((size_t)NBKT_MAX * 4);
    (void)ws_size; (void)n_in; (void)out_size;

    const int gA  = Npad / 128;
    const int gAs = NSpad / 128;
    const int gW  = (N + 1) / 2;
    const int chunk = (Et + PREP_BINA_BLKS - 1) / PREP_BINA_BLKS;

    // 1. zero bucket counters (2 KB)
    hipMemsetAsync(bktcnt, 0, (size_t)NBKT_MAX * 4, stream);
    // 2. merged prep: binA (first, full occupancy) + 14 weight transposes + X/Xs casts
    {
        WT14 wt;
        wt.src[0] = W_qkv; wt.dst[0] = WTq;          wt.nc[0] = 384; wt.coff[0] = 0;
        wt.src[1] = W_qkv; wt.dst[1] = WTq + 16384;  wt.nc[1] = 384; wt.coff[1] = 128;
        wt.src[2] = W_qkv; wt.dst[2] = WTq + 32768;  wt.nc[2] = 384; wt.coff[2] = 256;
        wt.src[3] = W_kv;  wt.dst[3] = WTkv;         wt.nc[3] = 256; wt.coff[3] = 0;
        wt.src[4] = W_kv;  wt.dst[4] = WTkv + 16384; wt.nc[4] = 256; wt.coff[4] = 128;
        wt.src[5] = W_gate;     wt.dst[5] = WTg;  wt.nc[5] = 128; wt.coff[5] = 0;
        wt.src[6] = W_o;        wt.dst[6] = WTo;  wt.nc[6] = 128; wt.coff[6] = 0;
        wt.src[7] = W_q;        wt.dst[7] = WTq2; wt.nc[7] = 128; wt.coff[7] = 0;
        wt.src[8] = W_gate_tgt; wt.dst[8] = WTgt; wt.nc[8] = 128; wt.coff[8] = 0;
        wt.src[9] = W_gate_src; wt.dst[9] = WTgs; wt.nc[9] = 128; wt.coff[9] = 0;
        wt.src[10]= W_o2;       wt.dst[10]= WTo2; wt.nc[10]= 128; wt.coff[10]= 0;
        wt.src[11]= w_bias;     wt.dst[11]= WTb1; wt.nc[11]= 8;   wt.coff[11]= 0;
        wt.src[12]= w_bias_tgt; wt.dst[12]= WTbt; wt.nc[12]= 8;   wt.coff[12]= 0;
        wt.src[13]= w_bias_src; wt.dst[13]= WTbs; wt.nc[13]= 8;   wt.coff[13]= 0;
        prep_k<<<PREP_BINA_BLKS + PREP_WT_BLKS + PREP_CAST_BLKS, 256, 0, stream>>>(
            X, Xb, N * 32, Xs, Xsb, NS * 32, wt,
            nbr_src, nbr_dst, inc_tgt, inc_src,
            bktcnt, tmp, E1, E2, N, shift, nbkt, chunk);
    }

    // 3. stage-1 projections + binD pseudo-job (grid-parallel; nbkt <= gA)
    {
        GemmJobs jb{};
        jb.j[0] = { Xb, WTq,         nullptr, nullptr, nullptr, nullptr, nullptr, Qb,  N, M_QS };
        jb.j[1] = { Xb, WTq + 16384, nullptr, nullptr, nullptr, nullptr, nullptr, kvi, N, M_KVIK };
        jb.j[2] = { Xb, WTq + 32768, nullptr, nullptr, nullptr, nullptr, nullptr, kvi, N, M_KVIV };
        jb.j[3] = { Xb, WTg,         b_gate,  nullptr, nullptr, nullptr, nullptr, g16, N, M_SIG };
        jb.j[4] = { Xb, WTb1,        nullptr, nullptr, nullptr, nullptr, nullptr, b8a, N, M_B8 };
        jb.j[5] = { (const uint16_t*)tmp, (const uint16_t*)bktcnt, (const float*)offs,
                    (const uint16_t*)ends, (const void*)sorted, nullptr, nullptr,
                    nullptr, 1 << 30, M_BIND, spb, NN };
        multi_gemm_k<<<dim3(gA, 6), 256, 0, stream>>>(jb);
    }
    // 4. self-attention
    self_attn_k<<<gW, 128, 0, stream>>>(Qb, kvi, b8a, offs, ends, sorted, g16, Awo, N);
    // 5. W_o GEMM + fused add+LN -> hb (bf16)
    {
        GemmJobs jb{};
        jb.j[0] = { Awo, WTo, nullptr, nullptr, X, ln1_g, ln1_b, hb, N, M_LN1 };
        multi_gemm_k<<<dim3(gA, 1), 256, 0, stream>>>(jb);
    }
    // 6. stage-2 projections: Qc, gate_tgt, KVI-K, V16, bias8_tgt
    {
        GemmJobs jb{};
        jb.j[0] = { hb,  WTq2,         nullptr,    nullptr, nullptr, nullptr, nullptr, Qcb,  N,  M_QS };
        jb.j[1] = { hb,  WTgt,         b_gate_tgt, nullptr, nullptr, nullptr, nullptr, g16,  N,  M_SIG };
        jb.j[2] = { Xsb, WTkv,         nullptr,    nullptr, nullptr, nullptr, nullptr, kvgi, NS, M_KVIK };
        jb.j[3] = { Xsb, WTkv + 16384, nullptr,    nullptr, nullptr, nullptr, nullptr, V16,  NS, M_BF16 };
        jb.j[4] = { hb,  WTbt,         nullptr,    nullptr, nullptr, nullptr, nullptr, b8a,  N,  M_B8 };
        multi_gemm_k<<<dim3(gAs, 5), 256, 0, stream>>>(jb);
    }
    // 7. gv = sigmoid(Xs@Wgs+b) * Vc -> interleaved V slot; bias8_src
    {
        GemmJobs jb{};
        jb.j[0] = { Xsb, WTgs, b_gate_src, V16, nullptr, nullptr, nullptr, kvgi, NS, M_GV };
        jb.j[1] = { Xsb, WTbs, nullptr, nullptr, nullptr, nullptr, nullptr, b8s,  NS, M_B8 };
        multi_gemm_k<<<dim3(gAs, 2), 256, 0, stream>>>(jb);
    }
    // 8. cross-attention
    cross_attn_k<<<gW, 128, 0, stream>>>(Qcb, b8a, kvgi, b8s, offs + N, ends + N, sorted, g16, Awo, N);
    // 9. W_o2 GEMM + fused add+LN -> d_out (f32)
    {
        GemmJobs jb{};
        jb.j[0] = { Awo, WTo2, nullptr, nullptr, hb, ln2_g, ln2_b, d_out, N, M_LN2 };
        multi_gemm_k<<<dim3(gA, 1), 256, 0, stream>>>(jb);
    }
}

// Round 14
// 290.462 us; speedup vs baseline: 1.0112x; 1.0112x over previous
//
#include <hip/hip_runtime.h>
#include <stdint.h>

// ---------------------------------------------------------------- helpers
__device__ __forceinline__ float bf_lo(uint32_t w) { return __uint_as_float(w << 16); }
__device__ __forceinline__ float bf_hi(uint32_t w) { return __uint_as_float(w & 0xffff0000u); }
__device__ __forceinline__ float bfu(uint16_t u) { return __uint_as_float((uint32_t)u << 16); }
__device__ __forceinline__ uint16_t f2bf(float f) {
    uint32_t u = __float_as_uint(f);
    uint32_t r = ((u >> 16) & 1u) + 0x7fffu;   // round-to-nearest-even
    return (uint16_t)((u + r) >> 16);
}
__device__ __forceinline__ uint32_t pk2bf(float a, float b) {
    return (uint32_t)f2bf(a) | ((uint32_t)f2bf(b) << 16);
}
__device__ __forceinline__ void gload_lds16(const void* g, void* l) {
    __builtin_amdgcn_global_load_lds(
        (const __attribute__((address_space(1))) void*)g,
        (__attribute__((address_space(3))) void*)l, 16, 0, 0);
}

typedef __attribute__((ext_vector_type(8))) short bf16x8;
typedef __attribute__((ext_vector_type(4))) float f32x4;

#define LOG2E 1.4426950408889634f
#define QSC2  (0.25f * LOG2E)      // fold 1/sqrt(dk) and log2e into Q

// gemm epilogue modes
#define M_BF16 0   // bf16 out [M][128]
#define M_QS   1   // bf16 out, scaled by QSC2
#define M_SIG  2   // sigmoid(acc+bias), bf16 out
#define M_KVIK 3   // interleaved K slot of [M][256]
#define M_KVIV 4   // interleaved V slot
#define M_GV   5   // sigmoid(acc+bias) * aux(bf16 [M][128]) -> interleaved V slot
#define M_LN1  6   // LN(residf32 + acc) -> bf16 out
#define M_LN2  7   // LN(residbf16 + acc) -> f32 out
#define M_B8   8   // cols 0..7 only -> f32 [M][8] (bias projections)
#define M_BIND 10  // CSR finalize pseudo-job (binD): no GEMM, grid-parallel

// ---------------------------------------------------------------- bucket capacity
#define NBKT_MAX 512
#define CAPSHIFT 13
#define BCAP (1 << CAPSHIFT)

struct GemmJob {
    const uint16_t* A; const uint16_t* WT; const float* bias;
    const uint16_t* aux; const void* resid;
    const float* lng; const float* lnb;
    void* out; int M; int mode; int i0; int i1;
};
struct GemmJobs { GemmJob j[9]; };

// stage a 128x128 bf16 tile (XOR-swizzled global source, linear LDS dest)
__device__ __forceinline__ void stage_tile(const uint16_t* __restrict__ g,
                                           uint16_t* lds, int tid, int wid)
{
#pragma unroll
    for (int it = 0; it < 8; ++it) {
        int idx = it * 256 + tid;
        int r = idx >> 4, c = idx & 15;
        int gc = c ^ (r & 7);
        gload_lds16(g + (size_t)r * 128 + gc * 8,
                    lds + (size_t)(it * 256 + wid * 64) * 8);
    }
}

// ---------------------------------------------------------------- MFMA GEMM (multi-job via blockIdx.y, per-job A/M)
__global__ __launch_bounds__(256) void multi_gemm_k(GemmJobs jobs)
{
    __shared__ uint16_t As[128 * 128];
    __shared__ uint16_t Ws[128 * 128];
    const GemmJob jb = jobs.j[blockIdx.y];
    const int tid = threadIdx.x;
    const int wid = tid >> 6;
    const int lane = tid & 63;
    const int mode = jb.mode;

    if (mode == M_BIND) {
        // binD: per-bucket per-segment hist + LDS scan -> offs/ends, then scatter
        const uint2* tmp   = (const uint2*)jb.A;
        const int* bktcnt  = (const int*)jb.WT;
        int* offs          = (int*)jb.bias;
        int* ends          = (int*)jb.aux;
        int* sorted        = (int*)jb.resid;
        const int spb = jb.i0, NN = jb.i1;
        int* sh  = (int*)As;               // spb ints
        int* wtb = (int*)Ws;               // 4 ints
        int b = blockIdx.x, t = tid;
        int s0 = b * spb;
        if (s0 >= NN) return;
        int segs = min(spb, NN - s0);
        int p0 = b << CAPSHIFT;
        int p1 = p0 + bktcnt[b];
        for (int i = t; i < segs; i += 256) sh[i] = 0;
        __syncthreads();
        for (int i = p0 + t; i < p1; i += 256)
            atomicAdd(&sh[(int)tmp[i].x - s0], 1);
        __syncthreads();
        int e_per = (spb + 255) >> 8;
        int loc[4], cv[4]; int ls = 0;
#pragma unroll 4
        for (int j = 0; j < 4; ++j) {
            if (j < e_per) {
                int idx = t * e_per + j;
                int v = (idx < segs) ? sh[idx] : 0;
                loc[j] = ls; cv[j] = v; ls += v;
            }
        }
        int sc = ls;
#pragma unroll
        for (int o = 1; o < 64; o <<= 1) { int x = __shfl_up(sc, o); if (lane >= o) sc += x; }
        if (lane == 63) wtb[wid] = sc;
        __syncthreads();
        int add = 0;
        for (int i = 0; i < wid; i++) add += wtb[i];
        int texcl = add + sc - ls;
#pragma unroll 4
        for (int j = 0; j < 4; ++j) {
            if (j < e_per) {
                int idx = t * e_per + j;
                if (idx < segs) {
                    int pos = p0 + texcl + loc[j];
                    offs[s0 + idx] = pos;
                    ends[s0 + idx] = pos + cv[j];
                    sh[idx] = pos;        // becomes cursor
                }
            }
        }
        __syncthreads();
        for (int i = p0 + t; i < p1; i += 256) {
            uint2 pr = tmp[i];
            int p = atomicAdd(&sh[(int)pr.x - s0], 1);
            sorted[p] = (int)pr.y;
        }
        return;
    }

    const int m0 = blockIdx.x * 128;
    if (m0 >= jb.M) return;
    const int M = jb.M;

    stage_tile(jb.A + (size_t)m0 * 128, As, tid, wid);
    stage_tile(jb.WT, Ws, tid, wid);
    __syncthreads();

    const int wr = wid >> 1, wc = wid & 1;
    const int l15 = lane & 15, l4 = lane >> 4;

    if (mode == M_B8) {
        // only cols 0..15 of WT are nonzero -> 16 MFMAs
        f32x4 acc[4];
#pragma unroll
        for (int i = 0; i < 4; i++) acc[i] = (f32x4){0.f, 0.f, 0.f, 0.f};
#pragma unroll
        for (int kk = 0; kk < 4; ++kk) {
            bf16x8 af0;
            {
                int r = l15;
                int cc = (kk * 4 + l4) ^ (r & 7);
                af0 = *(const bf16x8*)(Ws + r * 128 + cc * 8);
            }
#pragma unroll
            for (int mi = 0; mi < 4; ++mi) {
                int r = wr * 64 + mi * 16 + l15;
                int cc = (kk * 4 + l4) ^ (r & 7);
                bf16x8 bf = *(const bf16x8*)(As + r * 128 + cc * 8);
                acc[mi] = __builtin_amdgcn_mfma_f32_16x16x32_bf16(af0, bf, acc[mi], 0, 0, 0);
            }
        }
        if (wc == 0 && l4 < 2) {
#pragma unroll
            for (int mi = 0; mi < 4; ++mi) {
                int gm = m0 + wr * 64 + mi * 16 + l15;
                if (gm < M) {
                    f32x4 v = acc[mi];
                    *(float4*)((float*)jb.out + (size_t)gm * 8 + l4 * 4) =
                        make_float4(v.x, v.y, v.z, v.w);
                }
            }
        }
        return;
    }

    f32x4 acc[4][4];
#pragma unroll
    for (int i = 0; i < 4; i++)
#pragma unroll
        for (int j = 0; j < 4; j++) acc[i][j] = (f32x4){0.f, 0.f, 0.f, 0.f};

#pragma unroll
    for (int kk = 0; kk < 4; ++kk) {
        bf16x8 af[4], bff[4];
#pragma unroll
        for (int ni = 0; ni < 4; ++ni) {
            int r = wc * 64 + ni * 16 + l15;
            int cc = (kk * 4 + l4) ^ (r & 7);
            af[ni] = *(const bf16x8*)(Ws + r * 128 + cc * 8);
        }
#pragma unroll
        for (int mi = 0; mi < 4; ++mi) {
            int r = wr * 64 + mi * 16 + l15;
            int cc = (kk * 4 + l4) ^ (r & 7);
            bff[mi] = *(const bf16x8*)(As + r * 128 + cc * 8);
        }
#pragma unroll
        for (int ni = 0; ni < 4; ++ni)
#pragma unroll
            for (int mi = 0; mi < 4; ++mi)
                acc[ni][mi] = __builtin_amdgcn_mfma_f32_16x16x32_bf16(
                    af[ni], bff[mi], acc[ni][mi], 0, 0, 0);
    }

    if (mode == M_LN1 || mode == M_LN2) {
        __syncthreads();                      // all waves done reading Ws
        float* redS = (float*)Ws;             // [128][2]
        float* redQ = redS + 256;             // [128][2]
        float ps[4], qs[4];
#pragma unroll
        for (int mi = 0; mi < 4; ++mi) {
            int row = wr * 64 + mi * 16 + l15;
            int gm = m0 + row;
            float sum = 0.f, sq = 0.f;
#pragma unroll
            for (int ni = 0; ni < 4; ++ni) {
                int gn = wc * 64 + ni * 16 + l4 * 4;
                float r0 = 0.f, r1 = 0.f, r2 = 0.f, r3 = 0.f;
                if (gm < M) {
                    if (mode == M_LN1) {
                        float4 rv = *(const float4*)((const float*)jb.resid + (size_t)gm * 128 + gn);
                        r0 = rv.x; r1 = rv.y; r2 = rv.z; r3 = rv.w;
                    } else {
                        ushort4 rv = *(const ushort4*)((const uint16_t*)jb.resid + (size_t)gm * 128 + gn);
                        r0 = bfu(rv.x); r1 = bfu(rv.y); r2 = bfu(rv.z); r3 = bfu(rv.w);
                    }
                }
                f32x4 t = acc[ni][mi];
                t.x += r0; t.y += r1; t.z += r2; t.w += r3;
                acc[ni][mi] = t;
                sum += t.x + t.y + t.z + t.w;
                sq  += t.x * t.x + t.y * t.y + t.z * t.z + t.w * t.w;
            }
            sum += __shfl_xor(sum, 16); sum += __shfl_xor(sum, 32);
            sq  += __shfl_xor(sq, 16);  sq  += __shfl_xor(sq, 32);
            ps[mi] = sum; qs[mi] = sq;
        }
        if (l4 == 0) {
#pragma unroll
            for (int mi = 0; mi < 4; ++mi) {
                int row = wr * 64 + mi * 16 + l15;
                redS[row * 2 + wc] = ps[mi];
                redQ[row * 2 + wc] = qs[mi];
            }
        }
        __syncthreads();
#pragma unroll
        for (int mi = 0; mi < 4; ++mi) {
            int row = wr * 64 + mi * 16 + l15;
            int gm = m0 + row;
            if (gm >= M) continue;
            float S = redS[row * 2] + redS[row * 2 + 1];
            float Q = redQ[row * 2] + redQ[row * 2 + 1];
            float mean = S * (1.f / 128.f);
            float var  = Q * (1.f / 128.f) - mean * mean;
            float rstd = rsqrtf(var + 1e-5f);
#pragma unroll
            for (int ni = 0; ni < 4; ++ni) {
                int gn = wc * 64 + ni * 16 + l4 * 4;
                float4 gg = *(const float4*)(jb.lng + gn);
                float4 bb = *(const float4*)(jb.lnb + gn);
                f32x4 t = acc[ni][mi];
                float o0 = gg.x * (t.x - mean) * rstd + bb.x;
                float o1 = gg.y * (t.y - mean) * rstd + bb.y;
                float o2 = gg.z * (t.z - mean) * rstd + bb.z;
                float o3 = gg.w * (t.w - mean) * rstd + bb.w;
                if (mode == M_LN1) {
                    ushort4 o;
                    o.x = f2bf(o0); o.y = f2bf(o1); o.z = f2bf(o2); o.w = f2bf(o3);
                    *(ushort4*)((uint16_t*)jb.out + (size_t)gm * 128 + gn) = o;
                } else {
                    *(float4*)((float*)jb.out + (size_t)gm * 128 + gn) =
                        make_float4(o0, o1, o2, o3);
                }
            }
        }
        return;
    }

#pragma unroll
    for (int mi = 0; mi < 4; ++mi) {
        int gm = m0 + wr * 64 + mi * 16 + l15;
        if (gm >= M) continue;
#pragma unroll
        for (int ni = 0; ni < 4; ++ni) {
            int gn = wc * 64 + ni * 16 + l4 * 4;
            f32x4 v = acc[ni][mi];
            if (mode == M_SIG || mode == M_GV) {
                float4 bb = *(const float4*)(jb.bias + gn);
                v.x = 1.f / (1.f + __expf(-(v.x + bb.x)));
                v.y = 1.f / (1.f + __expf(-(v.y + bb.y)));
                v.z = 1.f / (1.f + __expf(-(v.z + bb.z)));
                v.w = 1.f / (1.f + __expf(-(v.w + bb.w)));
            }
            if (mode == M_QS) { v.x *= QSC2; v.y *= QSC2; v.z *= QSC2; v.w *= QSC2; }
            if (mode == M_GV) {
                ushort4 vs = *(const ushort4*)(jb.aux + (size_t)gm * 128 + gn);
                v.x *= bfu(vs.x); v.y *= bfu(vs.y); v.z *= bfu(vs.z); v.w *= bfu(vs.w);
            }
            if (mode == M_KVIK || mode == M_KVIV || mode == M_GV) {
                int which = (mode == M_KVIK) ? 0 : 2;
                uint16_t* op = (uint16_t*)jb.out + (size_t)gm * 256 + gn * 2 + which;
                *reinterpret_cast<uint32_t*>(op)     = pk2bf(v.x, v.y);
                *reinterpret_cast<uint32_t*>(op + 4) = pk2bf(v.z, v.w);
            } else {
                ushort4 o;
                o.x = f2bf(v.x); o.y = f2bf(v.y); o.z = f2bf(v.z); o.w = f2bf(v.w);
                *reinterpret_cast<ushort4*>((uint16_t*)jb.out + (size_t)gm * 128 + gn) = o;
            }
        }
    }
}

// ---------------------------------------------------------------- merged prep: binA FIRST, then weight transposes, then casts
#define PREP_BINA_BLKS 512
#define PREP_WT_BLKS   896    // 14 jobs x 64 blocks
#define PREP_CAST_BLKS 1536

struct WT14 { const float* src[14]; uint16_t* dst[14]; int nc[14]; int coff[14]; };

__global__ __launch_bounds__(256) void prep_k(
    const float* __restrict__ X, uint16_t* __restrict__ Xb, int n1,
    const float* __restrict__ Xs, uint16_t* __restrict__ Xsb, int n2,
    WT14 wt,
    const int* __restrict__ s1, const int* __restrict__ p1,
    const int* __restrict__ s2, const int* __restrict__ p2,
    int* __restrict__ bktcnt, uint2* __restrict__ tmp,
    int E1, int E2, int N, int shift, int nbkt, int chunk)
{
    __shared__ int hist[NBKT_MAX];
    __shared__ int lcur[NBKT_MAX];
    int bx = blockIdx.x;
    int t = threadIdx.x;
    if (bx < PREP_BINA_BLKS) {
        // binA: bucket-partition (seg,pay) pairs into fixed-capacity buckets
        int bid = bx;
        int Et = E1 + E2;
        int base = bid * chunk;
        int end = min(base + chunk, Et);
        for (int i = t; i < nbkt; i += 256) hist[i] = 0;
        __syncthreads();
        for (int i = base + t; i < end; i += 256) {
            int seg = (i < E1) ? s1[i] : N + s2[i - E1];
            atomicAdd(&hist[seg >> shift], 1);
        }
        __syncthreads();
        for (int i = t; i < nbkt; i += 256) {
            int c = hist[i];
            lcur[i] = (i << CAPSHIFT) + (c ? atomicAdd(&bktcnt[i], c) : 0);
        }
        __syncthreads();
        for (int i = base + t; i < end; i += 256) {
            int seg, pay;
            if (i < E1) { seg = s1[i]; pay = p1[i]; }
            else        { seg = N + s2[i - E1]; pay = p2[i - E1]; }
            int p = atomicAdd(&lcur[seg >> shift], 1);
            tmp[p] = make_uint2((uint32_t)seg, (uint32_t)pay);
        }
    } else if (bx < PREP_BINA_BLKS + PREP_WT_BLKS) {
        int pb = bx - PREP_BINA_BLKS;
        int y = pb >> 6, xx = pb & 63;
        const float* W = wt.src[y];
        uint16_t* WT = wt.dst[y];
        int nc = wt.nc[y], coff = wt.coff[y];
        int i = xx * 256 + t;
        int k = i >> 7, n = i & 127;
        float v;
        if (nc == 8) v = (n < 8) ? W[k * 8 + n] * LOG2E : 0.f;
        else         v = W[(size_t)k * nc + coff + n];
        WT[(size_t)n * 128 + k] = f2bf(v);
    } else {
        int i = (bx - PREP_BINA_BLKS - PREP_WT_BLKS) * 256 + t;
        int stride = PREP_CAST_BLKS * 256;
        for (; i < n1 + n2; i += stride) {
            float4 v;
            ushort4 o;
            if (i < n1) v = reinterpret_cast<const float4*>(X)[i];
            else        v = reinterpret_cast<const float4*>(Xs)[i - n1];
            o.x = f2bf(v.x); o.y = f2bf(v.y); o.z = f2bf(v.z); o.w = f2bf(v.w);
            if (i < n1) reinterpret_cast<ushort4*>(Xb)[i] = o;
            else        reinterpret_cast<ushort4*>(Xsb)[i - n1] = o;
        }
    }
}

// ---------------------------------------------------------------- self-attention (scalar index path, 8-edge batches)
#define SSTEP(KV, ACC)                                                           \
    {                                                                            \
        float s = q0 * bf_lo(KV.x) + q1 * bf_hi(KV.x);                           \
        s += __shfl_xor(s, 1); s += __shfl_xor(s, 2); s += __shfl_xor(s, 4);     \
        float w = exp2f(s + bs);                                                 \
        pa##ACC = fmaf(w, bf_lo(KV.y), pa##ACC);                                 \
        pb##ACC = fmaf(w, bf_hi(KV.y), pb##ACC);                                 \
        dn##ACC += w;                                                            \
    }

__global__ __launch_bounds__(128) void self_attn_k(
    const uint16_t* __restrict__ Qb, const uint16_t* __restrict__ kvi,
    const float* __restrict__ bias1,
    const int* __restrict__ offs, const int* __restrict__ ends,
    const int* __restrict__ sdst,
    const uint16_t* __restrict__ g16, uint16_t* __restrict__ Aout, int N)
{
    int lane = threadIdx.x & 63;
    int n = blockIdx.x * 2 + (threadIdx.x >> 6);
    if (n >= N) return;
    const int lane4 = lane * 4;
    uint32_t qw = *reinterpret_cast<const uint32_t*>(Qb + (size_t)n * 128 + 2 * lane);
    float q0 = bf_lo(qw), q1 = bf_hi(qw);
    float bs = bias1[(size_t)n * 8 + (lane >> 3)];
    int e0 = offs[n], e1 = ends[n];
    float dn0 = 0.f, pa0 = 0.f, pb0 = 0.f;
    float dn1 = 0.f, pa1 = 0.f, pb1 = 0.f;
    float dn2 = 0.f, pa2 = 0.f, pb2 = 0.f;
    float dn3 = 0.f, pa3 = 0.f, pb3 = 0.f;
    float dn4 = 0.f, pa4 = 0.f, pb4 = 0.f;
    float dn5 = 0.f, pa5 = 0.f, pb5 = 0.f;
    float dn6 = 0.f, pa6 = 0.f, pb6 = 0.f;
    float dn7 = 0.f, pa7 = 0.f, pb7 = 0.f;
    int e = e0;
    for (; e + 8 <= e1; e += 8) {
        const int* sp = sdst + __builtin_amdgcn_readfirstlane(e);
        int d0 = __builtin_amdgcn_readfirstlane(sp[0]);
        int d1 = __builtin_amdgcn_readfirstlane(sp[1]);
        int d2 = __builtin_amdgcn_readfirstlane(sp[2]);
        int d3 = __builtin_amdgcn_readfirstlane(sp[3]);
        int d4 = __builtin_amdgcn_readfirstlane(sp[4]);
        int d5 = __builtin_amdgcn_readfirstlane(sp[5]);
        int d6 = __builtin_amdgcn_readfirstlane(sp[6]);
        int d7 = __builtin_amdgcn_readfirstlane(sp[7]);
        uint2 kv0 = *reinterpret_cast<const uint2*>(kvi + ((size_t)d0 << 8) + lane4);
        uint2 kv1 = *reinterpret_cast<const uint2*>(kvi + ((size_t)d1 << 8) + lane4);
        uint2 kv2 = *reinterpret_cast<const uint2*>(kvi + ((size_t)d2 << 8) + lane4);
        uint2 kv3 = *reinterpret_cast<const uint2*>(kvi + ((size_t)d3 << 8) + lane4);
        uint2 kv4 = *reinterpret_cast<const uint2*>(kvi + ((size_t)d4 << 8) + lane4);
        uint2 kv5 = *reinterpret_cast<const uint2*>(kvi + ((size_t)d5 << 8) + lane4);
        uint2 kv6 = *reinterpret_cast<const uint2*>(kvi + ((size_t)d6 << 8) + lane4);
        uint2 kv7 = *reinterpret_cast<const uint2*>(kvi + ((size_t)d7 << 8) + lane4);
        SSTEP(kv0, 0) SSTEP(kv1, 1) SSTEP(kv2, 2) SSTEP(kv3, 3)
        SSTEP(kv4, 4) SSTEP(kv5, 5) SSTEP(kv6, 6) SSTEP(kv7, 7)
    }
    for (; e + 4 <= e1; e += 4) {
        const int* sp = sdst + __builtin_amdgcn_readfirstlane(e);
        int d0 = __builtin_amdgcn_readfirstlane(sp[0]);
        int d1 = __builtin_amdgcn_readfirstlane(sp[1]);
        int d2 = __builtin_amdgcn_readfirstlane(sp[2]);
        int d3 = __builtin_amdgcn_readfirstlane(sp[3]);
        uint2 kv0 = *reinterpret_cast<const uint2*>(kvi + ((size_t)d0 << 8) + lane4);
        uint2 kv1 = *reinterpret_cast<const uint2*>(kvi + ((size_t)d1 << 8) + lane4);
        uint2 kv2 = *reinterpret_cast<const uint2*>(kvi + ((size_t)d2 << 8) + lane4);
        uint2 kv3 = *reinterpret_cast<const uint2*>(kvi + ((size_t)d3 << 8) + lane4);
        SSTEP(kv0, 0) SSTEP(kv1, 1) SSTEP(kv2, 2) SSTEP(kv3, 3)
    }
    for (; e < e1; ++e) {
        int d0 = __builtin_amdgcn_readfirstlane(sdst[__builtin_amdgcn_readfirstlane(e)]);
        uint2 kv0 = *reinterpret_cast<const uint2*>(kvi + ((size_t)d0 << 8) + lane4);
        SSTEP(kv0, 0)
    }
    float den = ((dn0 + dn1) + (dn2 + dn3)) + ((dn4 + dn5) + (dn6 + dn7));
    float a0 = ((pa0 + pa1) + (pa2 + pa3)) + ((pa4 + pa5) + (pa6 + pa7));
    float a1 = ((pb0 + pb1) + (pb2 + pb3)) + ((pb4 + pb5) + (pb6 + pb7));
    float inv = 1.f / (den + 1e-30f);
    uint32_t gw = *reinterpret_cast<const uint32_t*>(g16 + (size_t)n * 128 + 2 * lane);
    a0 *= inv * bf_lo(gw); a1 *= inv * bf_hi(gw);
    *reinterpret_cast<uint32_t*>(Aout + (size_t)n * 128 + 2 * lane) = pk2bf(a0, a1);
}

// ---------------------------------------------------------------- cross-attention (scalar index path, 8-edge batches, V pre-gated)
#define CSTEP(KV, BSS, ACC)                                                      \
    {                                                                            \
        float s = q0 * bf_lo(KV.x) + q1 * bf_hi(KV.x);                           \
        s += __shfl_xor(s, 1); s += __shfl_xor(s, 2); s += __shfl_xor(s, 4);     \
        float w = exp2f(s + bt + BSS);                                           \
        pa##ACC = fmaf(w, bf_lo(KV.y), pa##ACC);                                 \
        pb##ACC = fmaf(w, bf_hi(KV.y), pb##ACC);                                 \
        dn##ACC += w;                                                            \
    }

__global__ __launch_bounds__(128) void cross_attn_k(
    const uint16_t* __restrict__ Qcb, const float* __restrict__ bias_t,
    const uint16_t* __restrict__ kvgi, const float* __restrict__ bias_s,
    const int* __restrict__ offs, const int* __restrict__ ends,
    const int* __restrict__ ssrc,
    const uint16_t* __restrict__ g16, uint16_t* __restrict__ Aout, int N)
{
    int lane = threadIdx.x & 63;
    int n = blockIdx.x * 2 + (threadIdx.x >> 6);
    if (n >= N) return;
    const int lane4 = lane * 4;
    const int head = lane >> 3;
    uint32_t qw = *reinterpret_cast<const uint32_t*>(Qcb + (size_t)n * 128 + 2 * lane);
    float q0 = bf_lo(qw), q1 = bf_hi(qw);
    float bt = bias_t[(size_t)n * 8 + head];
    int e0 = offs[n], e1 = ends[n];
    float dn0 = 0.f, pa0 = 0.f, pb0 = 0.f;
    float dn1 = 0.f, pa1 = 0.f, pb1 = 0.f;
    float dn2 = 0.f, pa2 = 0.f, pb2 = 0.f;
    float dn3 = 0.f, pa3 = 0.f, pb3 = 0.f;
    float dn4 = 0.f, pa4 = 0.f, pb4 = 0.f;
    float dn5 = 0.f, pa5 = 0.f, pb5 = 0.f;
    float dn6 = 0.f, pa6 = 0.f, pb6 = 0.f;
    float dn7 = 0.f, pa7 = 0.f, pb7 = 0.f;
    int e = e0;
    for (; e + 8 <= e1; e += 8) {
        const int* sp = ssrc + __builtin_amdgcn_readfirstlane(e);
        int d0 = __builtin_amdgcn_readfirstlane(sp[0]);
        int d1 = __builtin_amdgcn_readfirstlane(sp[1]);
        int d2 = __builtin_amdgcn_readfirstlane(sp[2]);
        int d3 = __builtin_amdgcn_readfirstlane(sp[3]);
        int d4 = __builtin_amdgcn_readfirstlane(sp[4]);
        int d5 = __builtin_amdgcn_readfirstlane(sp[5]);
        int d6 = __builtin_amdgcn_readfirstlane(sp[6]);
        int d7 = __builtin_amdgcn_readfirstlane(sp[7]);
        uint2 kv0 = *reinterpret_cast<const uint2*>(kvgi + ((size_t)d0 << 8) + lane4);
        uint2 kv1 = *reinterpret_cast<const uint2*>(kvgi + ((size_t)d1 << 8) + lane4);
        uint2 kv2 = *reinterpret_cast<const uint2*>(kvgi + ((size_t)d2 << 8) + lane4);
        uint2 kv3 = *reinterpret_cast<const uint2*>(kvgi + ((size_t)d3 << 8) + lane4);
        uint2 kv4 = *reinterpret_cast<const uint2*>(kvgi + ((size_t)d4 << 8) + lane4);
        uint2 kv5 = *reinterpret_cast<const uint2*>(kvgi + ((size_t)d5 << 8) + lane4);
        uint2 kv6 = *reinterpret_cast<const uint2*>(kvgi + ((size_t)d6 << 8) + lane4);
        uint2 kv7 = *reinterpret_cast<const uint2*>(kvgi + ((size_t)d7 << 8) + lane4);
        float bs0 = (bias_s + (size_t)d0 * 8)[head];
        float bs1 = (bias_s + (size_t)d1 * 8)[head];
        float bs2 = (bias_s + (size_t)d2 * 8)[head];
        float bs3 = (bias_s + (size_t)d3 * 8)[head];
        float bs4 = (bias_s + (size_t)d4 * 8)[head];
        float bs5 = (bias_s + (size_t)d5 * 8)[head];
        float bs6 = (bias_s + (size_t)d6 * 8)[head];
        float bs7 = (bias_s + (size_t)d7 * 8)[head];
        CSTEP(kv0, bs0, 0) CSTEP(kv1, bs1, 1) CSTEP(kv2, bs2, 2) CSTEP(kv3, bs3, 3)
        CSTEP(kv4, bs4, 4) CSTEP(kv5, bs5, 5) CSTEP(kv6, bs6, 6) CSTEP(kv7, bs7, 7)
    }
    for (; e + 4 <= e1; e += 4) {
        const int* sp = ssrc + __builtin_amdgcn_readfirstlane(e);
        int d0 = __builtin_amdgcn_readfirstlane(sp[0]);
        int d1 = __builtin_amdgcn_readfirstlane(sp[1]);
        int d2 = __builtin_amdgcn_readfirstlane(sp[2]);
        int d3 = __builtin_amdgcn_readfirstlane(sp[3]);
        uint2 kv0 = *reinterpret_cast<const uint2*>(kvgi + ((size_t)d0 << 8) + lane4);
        uint2 kv1 = *reinterpret_cast<const uint2*>(kvgi + ((size_t)d1 << 8) + lane4);
        uint2 kv2 = *reinterpret_cast<const uint2*>(kvgi + ((size_t)d2 << 8) + lane4);
        uint2 kv3 = *reinterpret_cast<const uint2*>(kvgi + ((size_t)d3 << 8) + lane4);
        float bs0 = (bias_s + (size_t)d0 * 8)[head];
        float bs1 = (bias_s + (size_t)d1 * 8)[head];
        float bs2 = (bias_s + (size_t)d2 * 8)[head];
        float bs3 = (bias_s + (size_t)d3 * 8)[head];
        CSTEP(kv0, bs0, 0) CSTEP(kv1, bs1, 1) CSTEP(kv2, bs2, 2) CSTEP(kv3, bs3, 3)
    }
    for (; e < e1; ++e) {
        int d0 = __builtin_amdgcn_readfirstlane(ssrc[__builtin_amdgcn_readfirstlane(e)]);
        uint2 kv0 = *reinterpret_cast<const uint2*>(kvgi + ((size_t)d0 << 8) + lane4);
        float bs0 = (bias_s + (size_t)d0 * 8)[head];
        CSTEP(kv0, bs0, 0)
    }
    float den = ((dn0 + dn1) + (dn2 + dn3)) + ((dn4 + dn5) + (dn6 + dn7));
    float a0 = ((pa0 + pa1) + (pa2 + pa3)) + ((pa4 + pa5) + (pa6 + pa7));
    float a1 = ((pb0 + pb1) + (pb2 + pb3)) + ((pb4 + pb5) + (pb6 + pb7));
    float inv = 1.f / (den + 1e-30f);
    uint32_t gw = *reinterpret_cast<const uint32_t*>(g16 + (size_t)n * 128 + 2 * lane);
    a0 *= inv * bf_lo(gw); a1 *= inv * bf_hi(gw);
    *reinterpret_cast<uint32_t*>(Aout + (size_t)n * 128 + 2 * lane) = pk2bf(a0, a1);
}

// ---------------------------------------------------------------- host
static inline size_t smax_(size_t a, size_t b) { return a > b ? a : b; }

extern "C" void kernel_launch(void* const* d_in, const int* in_sizes, int n_in,
                              void* d_out, int out_size, void* d_ws, size_t ws_size,
                              hipStream_t stream)
{
    const float* X          = (const float*)d_in[0];
    const float* Xs         = (const float*)d_in[1];
    const float* W_qkv      = (const float*)d_in[2];
    const float* w_bias     = (const float*)d_in[3];
    const float* W_gate     = (const float*)d_in[4];
    const float* b_gate     = (const float*)d_in[5];
    const float* W_o        = (const float*)d_in[6];
    const float* W_q        = (const float*)d_in[7];
    const float* W_kv       = (const float*)d_in[8];
    const float* w_bias_tgt = (const float*)d_in[9];
    const float* w_bias_src = (const float*)d_in[10];
    const float* W_gate_tgt = (const float*)d_in[11];
    const float* b_gate_tgt = (const float*)d_in[12];
    const float* W_gate_src = (const float*)d_in[13];
    const float* b_gate_src = (const float*)d_in[14];
    const float* W_o2       = (const float*)d_in[15];
    const float* ln1_g      = (const float*)d_in[16];
    const float* ln1_b      = (const float*)d_in[17];
    const float* ln2_g      = (const float*)d_in[18];
    const float* ln2_b      = (const float*)d_in[19];
    const int* nbr_src      = (const int*)d_in[20];
    const int* nbr_dst      = (const int*)d_in[21];
    const int* inc_tgt      = (const int*)d_in[22];
    const int* inc_src      = (const int*)d_in[23];

    const int N  = in_sizes[0] / 128;
    const int NS = in_sizes[1] / 128;
    const int E1 = in_sizes[20];
    const int E2 = in_sizes[22];
    const int Et = E1 + E2;
    const int NN = 2 * N;
    const int Npad  = (N + 127) & ~127;
    const int NSpad = (NS + 127) & ~127;

    // bucket geometry: spb segments/bucket, nbkt <= NBKT_MAX
    int shift = 8;
    while (((NN + (1 << shift) - 1) >> shift) > NBKT_MAX) ++shift;
    const int spb  = 1 << shift;
    const int nbkt = (NN + spb - 1) >> shift;

    char* ws = (char*)d_ws;
    size_t off = 0;
    auto alloc = [&](size_t bytes) -> void* {
        void* p = ws + off;
        off = (off + bytes + 255) & ~(size_t)255;
        return p;
    };

    uint16_t* Xb   = (uint16_t*)alloc((size_t)Npad * 128 * 2);
    uint16_t* Xsb  = (uint16_t*)alloc((size_t)NSpad * 128 * 2);
    uint16_t* WTq  = (uint16_t*)alloc((size_t)384 * 128 * 2);
    uint16_t* WTkv = (uint16_t*)alloc((size_t)256 * 128 * 2);
    uint16_t* WTg  = (uint16_t*)alloc((size_t)128 * 128 * 2);
    uint16_t* WTo  = (uint16_t*)alloc((size_t)128 * 128 * 2);
    uint16_t* WTq2 = (uint16_t*)alloc((size_t)128 * 128 * 2);
    uint16_t* WTgt = (uint16_t*)alloc((size_t)128 * 128 * 2);
    uint16_t* WTgs = (uint16_t*)alloc((size_t)128 * 128 * 2);
    uint16_t* WTo2 = (uint16_t*)alloc((size_t)128 * 128 * 2);
    uint16_t* WTb1 = (uint16_t*)alloc((size_t)128 * 128 * 2);   // w_bias pad
    uint16_t* WTbt = (uint16_t*)alloc((size_t)128 * 128 * 2);   // w_bias_tgt pad
    uint16_t* WTbs = (uint16_t*)alloc((size_t)128 * 128 * 2);   // w_bias_src pad
    // S1: phase-1 {Qb, kvi} in first Npad*384 elems; kvgi in the tail (concurrent-safe)
    uint16_t* S1 = (uint16_t*)alloc(((size_t)Npad * 384 + (size_t)NSpad * 256) * 2);
    uint16_t* Qb   = S1;
    uint16_t* kvi  = S1 + (size_t)Npad * 128;
    uint16_t* kvgi = S1 + (size_t)Npad * 384;
    // V16: reuse d_out as scratch when it fits (NS*256 bytes <= out_size*4); LN2 overwrites later
    uint16_t* V16;
    if ((size_t)NS * 256 <= (size_t)out_size * 4) V16 = (uint16_t*)d_out;
    else V16 = (uint16_t*)alloc((size_t)NSpad * 128 * 2);
    uint2* tmp  = (uint2*)alloc(((size_t)NBKT_MAX << CAPSHIFT) * 8);
    uint16_t* g16  = (uint16_t*)alloc((size_t)N * 128 * 2);
    uint16_t* Qcb  = (uint16_t*)alloc((size_t)N * 128 * 2);
    uint16_t* Awo  = (uint16_t*)alloc((size_t)Npad * 128 * 2);
    uint16_t* hb   = (uint16_t*)alloc((size_t)Npad * 128 * 2);
    float*    b8a  = (float*)alloc((size_t)N * 8 * 4);
    float*    b8s  = (float*)alloc((size_t)NS * 8 * 4);
    int* offs   = (int*)alloc((size_t)NN * 4);
    int* ends   = (int*)alloc((size_t)NN * 4);
    int* sorted = (int*)alloc(((size_t)NBKT_MAX << CAPSHIFT) * 4);
    int* bktcnt = (int*)alloc((size_t)NBKT_MAX * 4);
    (void)ws_size; (void)n_in;

    const int gA  = Npad / 128;
    const int gAs = NSpad / 128;
    const int gW  = (N + 1) / 2;
    const int chunk = (Et + PREP_BINA_BLKS - 1) / PREP_BINA_BLKS;

    // 1. zero bucket counters (2 KB)
    hipMemsetAsync(bktcnt, 0, (size_t)NBKT_MAX * 4, stream);
    // 2. merged prep: binA + 14 weight transposes + X/Xs casts
    {
        WT14 wt;
        wt.src[0] = W_qkv; wt.dst[0] = WTq;          wt.nc[0] = 384; wt.coff[0] = 0;
        wt.src[1] = W_qkv; wt.dst[1] = WTq + 16384;  wt.nc[1] = 384; wt.coff[1] = 128;
        wt.src[2] = W_qkv; wt.dst[2] = WTq + 32768;  wt.nc[2] = 384; wt.coff[2] = 256;
        wt.src[3] = W_kv;  wt.dst[3] = WTkv;         wt.nc[3] = 256; wt.coff[3] = 0;
        wt.src[4] = W_kv;  wt.dst[4] = WTkv + 16384; wt.nc[4] = 256; wt.coff[4] = 128;
        wt.src[5] = W_gate;     wt.dst[5] = WTg;  wt.nc[5] = 128; wt.coff[5] = 0;
        wt.src[6] = W_o;        wt.dst[6] = WTo;  wt.nc[6] = 128; wt.coff[6] = 0;
        wt.src[7] = W_q;        wt.dst[7] = WTq2; wt.nc[7] = 128; wt.coff[7] = 0;
        wt.src[8] = W_gate_tgt; wt.dst[8] = WTgt; wt.nc[8] = 128; wt.coff[8] = 0;
        wt.src[9] = W_gate_src; wt.dst[9] = WTgs; wt.nc[9] = 128; wt.coff[9] = 0;
        wt.src[10]= W_o2;       wt.dst[10]= WTo2; wt.nc[10]= 128; wt.coff[10]= 0;
        wt.src[11]= w_bias;     wt.dst[11]= WTb1; wt.nc[11]= 8;   wt.coff[11]= 0;
        wt.src[12]= w_bias_tgt; wt.dst[12]= WTbt; wt.nc[12]= 8;   wt.coff[12]= 0;
        wt.src[13]= w_bias_src; wt.dst[13]= WTbs; wt.nc[13]= 8;   wt.coff[13]= 0;
        prep_k<<<PREP_BINA_BLKS + PREP_WT_BLKS + PREP_CAST_BLKS, 256, 0, stream>>>(
            X, Xb, N * 32, Xs, Xsb, NS * 32, wt,
            nbr_src, nbr_dst, inc_tgt, inc_src,
            bktcnt, tmp, E1, E2, N, shift, nbkt, chunk);
    }

    // 3. stage-1 (N-side) + Xs-side h-independent projections + binD: 9 grid-parallel jobs
    {
        GemmJobs jb{};
        jb.j[0] = { Xb,  WTq,          nullptr, nullptr, nullptr, nullptr, nullptr, Qb,   N,  M_QS };
        jb.j[1] = { Xb,  WTq + 16384,  nullptr, nullptr, nullptr, nullptr, nullptr, kvi,  N,  M_KVIK };
        jb.j[2] = { Xb,  WTq + 32768,  nullptr, nullptr, nullptr, nullptr, nullptr, kvi,  N,  M_KVIV };
        jb.j[3] = { Xb,  WTg,          b_gate,  nullptr, nullptr, nullptr, nullptr, g16,  N,  M_SIG };
        jb.j[4] = { Xb,  WTb1,         nullptr, nullptr, nullptr, nullptr, nullptr, b8a,  N,  M_B8 };
        jb.j[5] = { (const uint16_t*)tmp, (const uint16_t*)bktcnt, (const float*)offs,
                    (const uint16_t*)ends, (const void*)sorted, nullptr, nullptr,
                    nullptr, 1 << 30, M_BIND, spb, NN };
        jb.j[6] = { Xsb, WTkv,         nullptr, nullptr, nullptr, nullptr, nullptr, kvgi, NS, M_KVIK };
        jb.j[7] = { Xsb, WTkv + 16384, nullptr, nullptr, nullptr, nullptr, nullptr, V16,  NS, M_BF16 };
        jb.j[8] = { Xsb, WTbs,         nullptr, nullptr, nullptr, nullptr, nullptr, b8s,  NS, M_B8 };
        multi_gemm_k<<<dim3(gAs, 9), 256, 0, stream>>>(jb);
    }
    // 4. self-attention
    self_attn_k<<<gW, 128, 0, stream>>>(Qb, kvi, b8a, offs, ends, sorted, g16, Awo, N);
    // 5. W_o GEMM + fused add+LN -> hb; GV = sigmoid(Xs@Wgs+b)*Vc -> kvgi V-slot
    {
        GemmJobs jb{};
        jb.j[0] = { Awo, WTo,  nullptr,    nullptr, X, ln1_g, ln1_b, hb,   N,  M_LN1 };
        jb.j[1] = { Xsb, WTgs, b_gate_src, V16,     nullptr, nullptr, nullptr, kvgi, NS, M_GV };
        multi_gemm_k<<<dim3(gAs, 2), 256, 0, stream>>>(jb);
    }
    // 6. stage-2 h-side projections: Qc, gate_tgt, bias8_tgt
    {
        GemmJobs jb{};
        jb.j[0] = { hb, WTq2, nullptr,    nullptr, nullptr, nullptr, nullptr, Qcb, N, M_QS };
        jb.j[1] = { hb, WTgt, b_gate_tgt, nullptr, nullptr, nullptr, nullptr, g16, N, M_SIG };
        jb.j[2] = { hb, WTbt, nullptr,    nullptr, nullptr, nullptr, nullptr, b8a, N, M_B8 };
        multi_gemm_k<<<dim3(gA, 3), 256, 0, stream>>>(jb);
    }
    // 7. cross-attention
    cross_attn_k<<<gW, 128, 0, stream>>>(Qcb, b8a, kvgi, b8s, offs + N, ends + N, sorted, g16, Awo, N);
    // 8. W_o2 GEMM + fused add+LN -> d_out (f32)
    {
        GemmJobs jb{};
        jb.j[0] = { Awo, WTo2, nullptr, nullptr, hb, ln2_g, ln2_b, d_out, N, M_LN2 };
        multi_gemm_k<<<dim3(gA, 1), 256, 0, stream>>>(jb);
    }
}